// Round 5
// baseline (155.641 us; speedup 1.0000x reference)
//
#include <hip/hip_runtime.h>
#include <math.h>

// UpPolyAct: out = c0 + c1*x + 0.25*c2*( z_ee + V + W )
//   R = X M^T, L = M X, OO = L M^T
//   z_eo=(R + s sRv^T/64)^2, z_oe=(L + Luv s^T/64)^2, z_oo=OO^2,
//   z_ee=(X + s t^T/64 + u s^T/64 + s s^T sig/4096)^2
//   U = z_oe + z_oo M,  V = M^T U,  W = z_eo M
// MFMA 32x32x16 bf16, transposed-domain chain (verified R2/R3).
// R4b: same as R4, with native ext-vector float4 for nontemporal stores
// (HIP_vector_type float4 is a class -> rejected by the builtin).

typedef short short8 __attribute__((ext_vector_type(8)));
typedef float f32x16 __attribute__((ext_vector_type(16)));
typedef float f32x4 __attribute__((ext_vector_type(4)));

#define LSH 68      // bf16 LDS row stride (rows 8B-aligned)
#define GSTR 136    // staggered g-copy stride (68 dwords == 4 mod 32)
#define FSTR 68     // f32 out-stage row stride (272 B, 16B-aligned rows)

__device__ __forceinline__ short f2bf(float f) {
  unsigned u = __float_as_uint(f);
  u += 0x7FFFu + ((u >> 16) & 1u);
  return (short)(u >> 16);
}
__device__ __forceinline__ unsigned pkbf(float a, float b) {
  unsigned ua = __float_as_uint(a); ua += 0x7FFFu + ((ua >> 16) & 1u);
  unsigned ub = __float_as_uint(b); ub += 0x7FFFu + ((ub >> 16) & 1u);
  return (ua >> 16) | (ub & 0xFFFF0000u);
}
__device__ __forceinline__ float bflo(unsigned u) {
  return __uint_as_float(u << 16);
}
__device__ __forceinline__ float bfhi(unsigned u) {
  return __uint_as_float(u & 0xFFFF0000u);
}
__device__ __forceinline__ short8 mk8(uint2 lo, uint2 hi) {
  union { unsigned u[4]; short8 s; } v;
  v.u[0] = lo.x; v.u[1] = lo.y; v.u[2] = hi.x; v.u[3] = hi.y;
  return v.s;
}
__device__ __forceinline__ short8 ldrow(const short* p) {
  return mk8(*(const uint2*)p, *(const uint2*)(p + 4));
}
// swizzled row read: 8-short chunk at units {u0, u0+1}, unit = 4 shorts,
// per-unit index XORed with sw = (row>>2)&15
__device__ __forceinline__ short8 ldrow_sw(const short* rowp, int u0, int sw) {
  return mk8(*(const uint2*)(rowp + 4 * (u0 ^ sw)),
             *(const uint2*)(rowp + 4 * ((u0 + 1) ^ sw)));
}
// value_j = g[ t ? -(basei+j) : (basei+j) & 63 ], basei = 16kk+8q-l31-32blk
__device__ __forceinline__ short8 tabfrag(const short* gtab, int t, int blk,
                                          int kk, int q, int l31) {
  const int s = 64 + 16 * kk + 8 * q - l31 - 32 * blk;  // in [1,120]
  const int p = s & 3;
  return ldrow(gtab + (t * 4 + p) * GSTR + (s - p));
}

__global__ void init_tables(float* ws) {
  __shared__ float g64s[64];
  const int tid = threadIdx.x;
  if (tid < 64) {
    const int d = 2 * tid + 1;
    double s = 1.0;
    for (int k = 1; k <= 32; ++k) {
      const int qq = (k * d) & 127;
      s += 2.0 * cos(M_PI * (double)qq / 64.0);
    }
    g64s[tid] = (float)(s / 64.0);
  }
  __syncthreads();
  if (tid < 128) ws[tid] = g64s[tid & 63];  // g2f duplicated f32
  short* gt = (short*)(ws + 128);           // 2 dirs x 4 phases x GSTR shorts
  for (int e = tid; e < 2 * 4 * GSTR; e += 256) {
    const int t = e / (4 * GSTR);
    const int rem = e - t * 4 * GSTR;
    const int p = rem / GSTR;
    const int m = rem - p * GSTR;
    const int li = m + p;
    const int gi = t ? ((-li) & 63) : (li & 63);
    gt[e] = f2bf(g64s[gi]);
  }
}

__global__ __launch_bounds__(256, 5) void uppolyact_kernel(
    const float* __restrict__ x, const float* __restrict__ coef,
    const float* __restrict__ ws, float* __restrict__ out) {
  __shared__ __align__(16) unsigned char arena[3 * 64 * LSH * 2];
  short* bufA = (short*)arena;                     // Xr -> Zeo
  short* bufB = (short*)(arena + 64 * LSH * 2);    // Xc(swizzled) -> Zoo
  short* bufC = (short*)(arena + 2 * 64 * LSH * 2);// Lr -> U^T
  float* fOut = (float*)(arena + 64 * LSH * 2);    // overlays bufB+bufC, 64*68*4
  __shared__ __align__(16) unsigned char tabs[2688];  // g2f(512B)+gtab(2176B)
  __shared__ float tp[256];  // t partials, then sRv partials
  __shared__ float up[256];  // u partials
  __shared__ float tvec[64], uvec[64];
  __shared__ float lrp[128];
  __shared__ float sigv;

  const float* g2f = (const float*)tabs;
  const short* gtab = (const short*)(tabs + 512);

  const int tid = threadIdx.x;
  const int lane = tid & 63;
  const int w = tid >> 6;
  const int q = lane >> 5;
  const int l31 = lane & 31;
  const int rb = w >> 1, cb = w & 1;
  const int icol = cb * 32 + l31;  // C-layout column for this lane
  const size_t base = (size_t)blockIdx.x * 4096;

  // ---- P0: load tables; stage X -> Xr (rows) + Xc (swizzled cols) bf16 ----
  if (tid < 168) *(float4*)&tabs[16 * tid] = ((const float4*)ws)[tid];
  {
    const float4* xv = (const float4*)(x + base);
#pragma unroll
    for (int e = 0; e < 4; ++e) {
      const int k4 = tid + 256 * e;
      const float4 v = xv[k4];
      const int r = k4 >> 4, c4 = k4 & 15, c = c4 << 2;
      const unsigned d0 = pkbf(v.x, v.y), d1 = pkbf(v.z, v.w);
      *(uint2*)&bufA[r * LSH + c] = make_uint2(d0, d1);
      // Xc swizzled: element (cr=c+d, i=r) at cr*LSH + 4*((r>>2)^c4) + (r&3)
      const int so = 4 * ((r >> 2) ^ c4) + (r & 3);
      bufB[(c + 0) * LSH + so] = (short)d0;
      bufB[(c + 1) * LSH + so] = (short)(d0 >> 16);
      bufB[(c + 2) * LSH + so] = (short)d1;
      bufB[(c + 3) * LSH + so] = (short)(d1 >> 16);
    }
  }
  __syncthreads();  // B1

  // ---- P1: Rt = M X^T, Lt = X^T M^T (MFMA); t/u partials; Luv reg-sums ----
  f32x16 Rt, Lt;
#pragma unroll
  for (int r = 0; r < 16; ++r) { Rt[r] = 0.0f; Lt[r] = 0.0f; }
  {
    const int rowA = 32 * rb + l31;
    const int swA = (rowA >> 2) & 15;
    const short* rowpA = &bufB[rowA * LSH];
#pragma unroll
    for (int kk = 0; kk < 4; ++kk) {
      const short8 aR = tabfrag(gtab, 1, rb, kk, q, l31);
      const short8 bR = ldrow(&bufA[(cb * 32 + l31) * LSH + kk * 16 + q * 8]);
      Rt = __builtin_amdgcn_mfma_f32_32x32x16_bf16(aR, bR, Rt, 0, 0, 0);
      const short8 aL = ldrow_sw(rowpA, 4 * kk + 2 * q, swA);
      const short8 bL = tabfrag(gtab, 1, cb, kk, q, l31);
      Lt = __builtin_amdgcn_mfma_f32_32x32x16_bf16(aL, bL, Lt, 0, 0, 0);
    }
  }
  {
    const int jj = tid & 63, pp = tid >> 6;
    const int swj = (jj >> 2) & 15;
    float tacc = 0.0f, uacc = 0.0f;
#pragma unroll
    for (int g4 = 0; g4 < 4; ++g4) {
      const uint2 dt = *(const uint2*)&bufB[jj * LSH + 4 * ((4 * pp + g4) ^ swj)];
      tacc += bflo(dt.x) - bfhi(dt.x) + bflo(dt.y) - bfhi(dt.y);
      const uint2 du = *(const uint2*)&bufA[jj * LSH + 16 * pp + 4 * g4];
      uacc += bflo(du.x) - bfhi(du.x) + bflo(du.y) - bfhi(du.y);
    }
    tp[pp * 64 + jj] = tacc;  // t[j] partial over i
    up[pp * 64 + jj] = uacc;  // u[i] partial over j
  }
  {
    float lp = 0.0f;  // Luv[i=icol] partial over jrow-half rb
#pragma unroll
    for (int r = 0; r < 16; ++r) lp += (r & 1) ? -Lt[r] : Lt[r];
    lp += __shfl_xor(lp, 32);
    if (q == 0) lrp[rb * 64 + icol] = lp;
  }
  __syncthreads();  // B2

  // ---- P2: write Lr (packed transpose-write); combine tvec/uvec ----
#pragma unroll
  for (int grp = 0; grp < 4; ++grp) {
    const unsigned d0 = pkbf(Lt[4 * grp + 0], Lt[4 * grp + 1]);
    const unsigned d1 = pkbf(Lt[4 * grp + 2], Lt[4 * grp + 3]);
    *(uint2*)&bufC[icol * LSH + 4 * q + 32 * rb + 8 * grp] = make_uint2(d0, d1);
  }
  if (tid < 64) {
    tvec[tid] = tp[tid] + tp[64 + tid] + tp[128 + tid] + tp[192 + tid];
  } else if (tid < 128) {
    const int i = tid - 64;
    uvec[i] = up[i] + up[64 + i] + up[128 + i] + up[192 + i];
  }
  __syncthreads();  // B3

  // ---- P3: OOt = M Lt; z_oo -> bufB; sRv partials; sig; extract x ----
  f32x16 OOt;
#pragma unroll
  for (int r = 0; r < 16; ++r) OOt[r] = 0.0f;
#pragma unroll
  for (int kk = 0; kk < 4; ++kk) {
    const short8 a = tabfrag(gtab, 1, rb, kk, q, l31);
    const short8 b = ldrow(&bufC[(cb * 32 + l31) * LSH + kk * 16 + q * 8]);
    OOt = __builtin_amdgcn_mfma_f32_32x32x16_bf16(a, b, OOt, 0, 0, 0);
  }
  {
    const int jj = tid & 63, pp = tid >> 6;
    float sp = 0.0f;  // sRv[j] = sum_m t[m] g[(j-m)&63], partial over m
#pragma unroll
    for (int mm = 0; mm < 16; ++mm) {
      const int m = 16 * pp + mm;
      sp += tvec[m] * g2f[64 + jj - m];
    }
    tp[pp * 64 + jj] = sp;  // reuse tp as sRv partials
  }
  if (tid >= 192) {  // sig = s^T X s, wave-3 butterfly over uvec
    const int i = tid - 192;
    float v = (i & 1) ? -uvec[i] : uvec[i];
#pragma unroll
    for (int off = 32; off >= 1; off >>= 1) v += __shfl_xor(v, off);
    if (i == 0) sigv = v;
  }
  unsigned xpk[8];  // packed bf16 x at this lane's 16 output positions
#pragma unroll
  for (int h = 0; h < 8; ++h) {
    const int r0 = 2 * h;
    const int irow = (r0 & 3) + 4 * q + 8 * (r0 >> 2) + 32 * rb;
    const unsigned lo = (unsigned short)bufA[irow * LSH + icol];
    const unsigned hi = (unsigned short)bufA[(irow + 1) * LSH + icol];
    xpk[h] = lo | (hi << 16);
  }
#pragma unroll
  for (int grp = 0; grp < 4; ++grp) {
    const unsigned d0 = pkbf(OOt[4 * grp + 0] * OOt[4 * grp + 0],
                             OOt[4 * grp + 1] * OOt[4 * grp + 1]);
    const unsigned d1 = pkbf(OOt[4 * grp + 2] * OOt[4 * grp + 2],
                             OOt[4 * grp + 3] * OOt[4 * grp + 3]);
    *(uint2*)&bufB[icol * LSH + 4 * q + 32 * rb + 8 * grp] = make_uint2(d0, d1);
  }
  __syncthreads();  // B4

  // ---- P4: z_eo -> bufA; Ut = z_oe + M^T z_oo; U^T -> bufC ----
  const float sgi = (icol & 1) ? -1.0f : 1.0f;
  const float luv_i = lrp[icol] + lrp[64 + icol];
  f32x16 Ut;
#pragma unroll
  for (int grp = 0; grp < 4; ++grp) {
    const int idx4 = 4 * q + 32 * rb + 8 * grp;
    const float4 s0 = *(const float4*)&tp[idx4];
    const float4 s1 = *(const float4*)&tp[64 + idx4];
    const float4 s2 = *(const float4*)&tp[128 + idx4];
    const float4 s3 = *(const float4*)&tp[192 + idx4];
    float zeo[4];
#pragma unroll
    for (int rr = 0; rr < 4; ++rr) {
      const int r = 4 * grp + rr;
      const float srv = (&s0.x)[rr] + (&s1.x)[rr] + (&s2.x)[rr] + (&s3.x)[rr];
      const float veo = Rt[r] + sgi * srv * (1.0f / 64.0f);
      zeo[rr] = veo * veo;
      const float sgj = (r & 1) ? -1.0f : 1.0f;
      const float voe = Lt[r] + luv_i * sgj * (1.0f / 64.0f);
      Ut[r] = voe * voe;
    }
    *(uint2*)&bufA[icol * LSH + idx4] =
        make_uint2(pkbf(zeo[0], zeo[1]), pkbf(zeo[2], zeo[3]));
  }
#pragma unroll
  for (int kk = 0; kk < 4; ++kk) {
    const short8 aU = tabfrag(gtab, 0, rb, kk, q, l31);
    const short8 bU = ldrow(&bufB[(cb * 32 + l31) * LSH + kk * 16 + q * 8]);
    Ut = __builtin_amdgcn_mfma_f32_32x32x16_bf16(aU, bU, Ut, 0, 0, 0);
  }
#pragma unroll
  for (int r = 0; r < 16; ++r) {
    const int jrow = (r & 3) + 4 * q + 8 * (r >> 2) + 32 * rb;
    bufC[jrow * LSH + icol] = f2bf(Ut[r]);  // U^T row-major
  }
  __syncthreads();  // B5

  // ---- P5: W = z_eo M; V = M^T U; epilogue compute ----
  f32x16 Wv, Vv;
#pragma unroll
  for (int r = 0; r < 16; ++r) { Wv[r] = 0.0f; Vv[r] = 0.0f; }
#pragma unroll
  for (int kk = 0; kk < 4; ++kk) {
    const short8 aW = ldrow(&bufA[(rb * 32 + l31) * LSH + kk * 16 + q * 8]);
    const short8 bW = tabfrag(gtab, 0, cb, kk, q, l31);
    Wv = __builtin_amdgcn_mfma_f32_32x32x16_bf16(aW, bW, Wv, 0, 0, 0);
    const short8 aV = tabfrag(gtab, 0, rb, kk, q, l31);
    const short8 bV = ldrow(&bufC[(cb * 32 + l31) * LSH + kk * 16 + q * 8]);
    Vv = __builtin_amdgcn_mfma_f32_32x32x16_bf16(aV, bV, Vv, 0, 0, 0);
  }
  const float c0 = coef[0], c1 = coef[1];
  const float c2q = 0.25f * coef[2];
  const float sgjc = (icol & 1) ? -1.0f : 1.0f;
  const float tj = tvec[icol];
#pragma unroll
  for (int grp = 0; grp < 4; ++grp) {
    const float4 uv = *(const float4*)&uvec[4 * q + 32 * rb + 8 * grp];
#pragma unroll
    for (int rr = 0; rr < 4; ++rr) {
      const int r = 4 * grp + rr;
      const float sgir = (r & 1) ? -1.0f : 1.0f;
      const float xg = (r & 1) ? bfhi(xpk[r >> 1]) : bflo(xpk[r >> 1]);
      const float vee = xg + (sgir * tj + (&uv.x)[rr] * sgjc) * (1.0f / 64.0f) +
                        sgir * sgjc * sigv * (1.0f / 4096.0f);
      Vv[r] = c0 + c1 * xg + c2q * (vee * vee + Vv[r] + Wv[r]);
    }
  }
  __syncthreads();  // B6 (all frag reads of bufB/bufC done -> overlay fOut)

  // ---- P6: stage f32 outputs, then coalesced nontemporal float4 stores ----
#pragma unroll
  for (int r = 0; r < 16; ++r) {
    const int irow = (r & 3) + 4 * q + 8 * (r >> 2) + 32 * rb;
    fOut[irow * FSTR + icol] = Vv[r];
  }
  __syncthreads();  // B7
  {
    f32x4* ov = (f32x4*)(out + base);
#pragma unroll
    for (int e = 0; e < 4; ++e) {
      const int idx4 = tid + 256 * e;
      const int row = idx4 >> 4, col4 = (idx4 & 15) << 2;
      const f32x4 v = *(const f32x4*)&fOut[row * FSTR + col4];
      __builtin_nontemporal_store(v, &ov[idx4]);
    }
  }
}

extern "C" void kernel_launch(void* const* d_in, const int* in_sizes, int n_in,
                              void* d_out, int out_size, void* d_ws,
                              size_t ws_size, hipStream_t stream) {
  const float* x = (const float*)d_in[0];
  const float* coef = (const float*)d_in[1];
  float* out = (float*)d_out;
  float* ws = (float*)d_ws;
  const int channels = out_size / 4096;  // 32*128 channels of 64x64
  init_tables<<<dim3(1), dim3(256), 0, stream>>>(ws);
  uppolyact_kernel<<<dim3(channels), dim3(256), 0, stream>>>(x, coef, ws, out);
}